// Round 3
// baseline (1754.185 us; speedup 1.0000x reference)
//
#include <hip/hip_runtime.h>

// Problem constants
#define B_ 32
#define S_ 2048
#define DA 32
#define DH 128
#define DS 64
#define DS2 4096
#define TKK 16

template <int CTRL>
__device__ __forceinline__ float dpp_add(float x) {
  int t = __builtin_amdgcn_update_dpp(0, __float_as_int(x), CTRL, 0xF, 0xF, true);
  return x + __int_as_float(t);
}
// sum over the 16 lanes of each row, result uniform within the row
__device__ __forceinline__ float row_sum16(float x) {
  x = dpp_add<0xB1>(x);
  x = dpp_add<0x4E>(x);
  x = dpp_add<0x141>(x);
  x = dpp_add<0x140>(x);
  return x;
}

// async global->LDS DMA, 16 B per lane (dest = wave-uniform base + lane*16)
__device__ __forceinline__ void gl2lds16(const float* g, float* l) {
  __builtin_amdgcn_global_load_lds(
      (const __attribute__((address_space(1))) void*)g,
      (__attribute__((address_space(3))) void*)l, 16, 0, 0);
}

// ---------------------------------------------------------------------------
// Shared-memory union. 512-thread blocks, ~97 KB -> 1 block/CU.
// GEMM: A staged in LDS (8 KB/stage, double-buffered); B (w2) is read
// DIRECTLY from global per-fragment -- the 8 KB/stage slab is L1-resident,
// so operand bandwidth is split LDS(A) + L1(B) instead of saturating LDS.
// ---------------------------------------------------------------------------
struct SharedRnn {
  float4 ring[6][16][64];   // 96 KB
  int flags[6];
  int cons;
};
struct SharedGemm {
  float As[2][TKK][128];    // 16 KB (A double-buffer)
  float4 part[256][17];     // 68 KB split-K combine buffer (padded rows)
};
struct SharedMlp {
  float a_t[DA][64];        // 8 KB
  float w0_l[DA][DH];       // 16 KB
  float h0t[DH][64];        // 32 KB
};
union SharedU {
  SharedRnn r;
  SharedGemm g;
  SharedMlp m;
};

// ---------------------------------------------------------------------------
// MLP tile, 512-thread version: 64 tokens -> h1t[f][tok] (transposed).
// ---------------------------------------------------------------------------
__device__ __forceinline__ void mlp_tile(
    const float* __restrict__ actions, const float* __restrict__ w0,
    const float* __restrict__ b0, const float* __restrict__ w1,
    const float* __restrict__ b1, float* __restrict__ h1t,
    int s_base, int M, int m0, SharedMlp& sm, int tid)
{
  {
    // 512 threads stage a_t in one pass: tok = tid>>3, kq = tid&7
    int tok = tid >> 3, kq = tid & 7;
    int tl = m0 + tok;
    int b = tl & 31, s = s_base + (tl >> 5);
    float4 v = *(const float4*)(actions + ((size_t)b * S_ + s) * DA + 4 * kq);
    sm.a_t[4 * kq + 0][tok] = v.x; sm.a_t[4 * kq + 1][tok] = v.y;
    sm.a_t[4 * kq + 2][tok] = v.z; sm.a_t[4 * kq + 3][tok] = v.w;
  }
#pragma unroll
  for (int q = 0; q < 2; ++q) {
    int g = tid + 512 * q;        // 1024 float4s of w0
    ((float4*)&sm.w0_l[0][0])[g] = ((const float4*)w0)[g];
  }
  __syncthreads();

  const int tm = tid & 15;        // token group: tokens 4*tm+mi
  const int tn = tid >> 4;        // 0..31: features 4*tn+ni

  float acc[4][4];
#pragma unroll
  for (int mi = 0; mi < 4; ++mi)
#pragma unroll
    for (int ni = 0; ni < 4; ++ni) acc[mi][ni] = 0.f;

#pragma unroll 4
  for (int k = 0; k < DA; ++k) {
    float4 a4 = *(const float4*)&sm.a_t[k][4 * tm];
    float4 w4 = *(const float4*)&sm.w0_l[k][4 * tn];
    float av[4] = {a4.x, a4.y, a4.z, a4.w};
    float wv[4] = {w4.x, w4.y, w4.z, w4.w};
#pragma unroll
    for (int mi = 0; mi < 4; ++mi)
#pragma unroll
      for (int ni = 0; ni < 4; ++ni) acc[mi][ni] += av[mi] * wv[ni];
  }
  {
    float4 b4 = *(const float4*)(b0 + 4 * tn);
    float bv[4] = {b4.x, b4.y, b4.z, b4.w};
#pragma unroll
    for (int mi = 0; mi < 4; ++mi)
#pragma unroll
      for (int ni = 0; ni < 4; ++ni)
        sm.h0t[4 * tn + ni][4 * tm + mi] = fmaxf(acc[mi][ni] + bv[ni], 0.f);
  }
  __syncthreads();

  float acc1[4][4];
#pragma unroll
  for (int mi = 0; mi < 4; ++mi)
#pragma unroll
    for (int ni = 0; ni < 4; ++ni) acc1[mi][ni] = 0.f;

#pragma unroll 4
  for (int k = 0; k < DH; ++k) {
    float4 h4 = *(const float4*)&sm.h0t[k][4 * tm];
    float4 w4 = *(const float4*)(w1 + (size_t)k * DH + 4 * tn);
    float av[4] = {h4.x, h4.y, h4.z, h4.w};
    float wv[4] = {w4.x, w4.y, w4.z, w4.w};
#pragma unroll
    for (int mi = 0; mi < 4; ++mi)
#pragma unroll
      for (int ni = 0; ni < 4; ++ni) acc1[mi][ni] += av[mi] * wv[ni];
  }
  {
    float4 b4 = *(const float4*)(b1 + 4 * tn);
    float bv[4] = {b4.x, b4.y, b4.z, b4.w};
#pragma unroll
    for (int ni = 0; ni < 4; ++ni) {
      float4 o;
      o.x = fmaxf(acc1[0][ni] + bv[ni], 0.f);
      o.y = fmaxf(acc1[1][ni] + bv[ni], 0.f);
      o.z = fmaxf(acc1[2][ni] + bv[ni], 0.f);
      o.w = fmaxf(acc1[3][ni] + bv[ni], 0.f);
      *(float4*)(h1t + (size_t)(4 * tn + ni) * M + m0 + 4 * tm) = o;
    }
  }
}

// ---------------------------------------------------------------------------
// Trans tile, 512-thread split-K, B-direct version: 128x128 tile at (m0,n0).
// Waves 0-3 accumulate k = 0..7 of each 16-k stage, waves 4-7 take k = 8..15.
// A comes from LDS (double-buffered gl2lds staging); B (w2) fragments are
// loaded straight from global -- the 16x128 stage slab is L1-resident, so
// LDS traffic halves (A only) and operand BW splits across LDS + L1.
// ---------------------------------------------------------------------------
__device__ __forceinline__ void trans_tile(
    const float* __restrict__ h1t, const float* __restrict__ w2,
    const float* __restrict__ b2, float* __restrict__ trans,
    int M, int n0, int m0, SharedGemm& sg, int tid)
{
  const int w  = tid >> 6;     // 0..7
  const int lw = tid & 63;

  // A staging only: 16 rows x 128 floats = 8 KB/stage; wave w stages rows 2w,2w+1
  auto aload = [&](int t, int buf) {
    const int kr = 2 * w + (lw >> 5);
    const int c4 = 4 * (lw & 31);
    gl2lds16(h1t + (size_t)(t * TKK + kr) * M + m0 + c4, &sg.As[buf][2 * w][0]);
  };

  aload(0, 0);

  const int sub = tid & 255;
  const int khalf = tid >> 8;        // 0: k 0..7 / 1: k 8..15 of each stage
  const int mg = sub >> 4;
  const int ng = sub & 15;
  float acc[8][8];
#pragma unroll
  for (int mi = 0; mi < 8; ++mi)
#pragma unroll
    for (int ni = 0; ni < 8; ++ni) acc[mi][ni] = 0.f;

  int buf = 0;
  const int kb = 8 * khalf;
  const float* w2p = w2 + n0 + 4 * ng + (size_t)kb * DS2;  // per-thread B base
  for (int t = 0; t < DH / TKK; ++t) {
    __syncthreads();
    if (t < DH / TKK - 1) aload(t + 1, buf ^ 1);
    const float* w2k = w2p + (size_t)t * TKK * DS2;
#pragma unroll
    for (int k8 = 0; k8 < 8; ++k8) {
      const int k = kb + k8;
      float4 b0v = *(const float4*)(w2k + (size_t)k8 * DS2);
      float4 b1v = *(const float4*)(w2k + (size_t)k8 * DS2 + 64);
      float4 a0 = *(const float4*)&sg.As[buf][k][8 * mg];
      float4 a1 = *(const float4*)&sg.As[buf][k][8 * mg + 4];
      float av[8] = {a0.x, a0.y, a0.z, a0.w, a1.x, a1.y, a1.z, a1.w};
      float bv[8] = {b0v.x, b0v.y, b0v.z, b0v.w, b1v.x, b1v.y, b1v.z, b1v.w};
#pragma unroll
      for (int mi = 0; mi < 8; ++mi)
#pragma unroll
        for (int ni = 0; ni < 8; ++ni) acc[mi][ni] += av[mi] * bv[ni];
    }
    buf ^= 1;
  }

  // split-K combine
  __syncthreads();
  if (khalf) {
#pragma unroll
    for (int mi = 0; mi < 8; ++mi) {
      sg.part[sub][2 * mi] =
          make_float4(acc[mi][0], acc[mi][1], acc[mi][2], acc[mi][3]);
      sg.part[sub][2 * mi + 1] =
          make_float4(acc[mi][4], acc[mi][5], acc[mi][6], acc[mi][7]);
    }
  }
  __syncthreads();
  if (!khalf) {
    float4 bb0 = *(const float4*)(b2 + n0 + 4 * ng);
    float4 bb1 = *(const float4*)(b2 + n0 + 64 + 4 * ng);
    float bv[8] = {bb0.x, bb0.y, bb0.z, bb0.w, bb1.x, bb1.y, bb1.z, bb1.w};
#pragma unroll
    for (int mi = 0; mi < 8; ++mi) {
      float4 p0 = sg.part[sub][2 * mi];
      float4 p1 = sg.part[sub][2 * mi + 1];
      float pv[8] = {p0.x, p0.y, p0.z, p0.w, p1.x, p1.y, p1.z, p1.w};
      float* dst = trans + (size_t)(m0 + 8 * mg + mi) * DS2 + n0;
#pragma unroll
      for (int q = 0; q < 2; ++q) {
        float4 o;
        o.x = acc[mi][4 * q + 0] + pv[4 * q + 0] + bv[4 * q + 0];
        o.y = acc[mi][4 * q + 1] + pv[4 * q + 1] + bv[4 * q + 1];
        o.z = acc[mi][4 * q + 2] + pv[4 * q + 2] + bv[4 * q + 2];
        o.w = acc[mi][4 * q + 3] + pv[4 * q + 3] + bv[4 * q + 3];
        *(float4*)(dst + 64 * q + 4 * ng) = o;
      }
    }
  }
}

// ---------------------------------------------------------------------------
// Standalone MLP kernel (chunk 0 priming)
// ---------------------------------------------------------------------------
__global__ __launch_bounds__(512) void k_mlp01(
    const float* __restrict__ actions, const float* __restrict__ w0,
    const float* __restrict__ b0, const float* __restrict__ w1,
    const float* __restrict__ b1, float* __restrict__ h1t,
    int s_base, int M)
{
  __shared__ SharedMlp sm;
  mlp_tile(actions, w0, b0, w1, b1, h1t, s_base, M, blockIdx.x * 64, sm,
           threadIdx.x);
}

// ---------------------------------------------------------------------------
// Combined pipelined kernel, launch index c = 0..nch:
//  blocks 0..31  : rnn for chunk c-1 (if c>0), reading trans[(c-1)%2]
//  blocks 32..255: trans tiles for chunk c (if c<nch): h1t[c%2] -> trans[c%2],
//                  then mlp tiles for chunk c+1 (if c+1<nch) -> h1t[(c+1)%2]
// ALL dependencies are cross-launch (stream-ordered); no cross-block sync.
// RNN keeps the R0-validated protocol: consumer = wave 0, producers =
// waves 1..3 (stride 3), waves 4..7 idle.
// ---------------------------------------------------------------------------
__global__ __launch_bounds__(512, 1) void k_comb(
    const float* __restrict__ actions, const float* __restrict__ w0,
    const float* __restrict__ b0, const float* __restrict__ w1,
    const float* __restrict__ b1, const float* __restrict__ w2,
    const float* __restrict__ b2, const float* __restrict__ init_hidden,
    float* __restrict__ trans0, float* __restrict__ trans1,
    float* __restrict__ h1t0, float* __restrict__ h1t1,
    float* __restrict__ hstate, float* __restrict__ out,
    int c, int SC, int nch)
{
  __shared__ SharedU sh;
  const int tid = threadIdx.x;
  const int M = SC * 32;

  if (blockIdx.x >= 32) {
    // -------------------- GEMM blocks --------------------
    const int bi = blockIdx.x - 32;   // 0..223 (R0 mapping; swizzle reverted)
    if (c < nch) {
      const float* h1t = (c & 1) ? h1t1 : h1t0;
      float* trans = (c & 1) ? trans1 : trans0;
      const int NJ = (M / 128) * (DS2 / 128);
      for (int j = bi; j < NJ; j += 224) {
        const int mt = j >> 5, nt = j & 31;
        trans_tile(h1t, w2, b2, trans, M, nt * 128, mt * 128, sh.g, tid);
        __syncthreads();
      }
      if (c + 1 < nch) {
        __syncthreads();
        float* h1n = ((c + 1) & 1) ? h1t1 : h1t0;
        for (int j = bi; j < M / 64; j += 224) {
          mlp_tile(actions, w0, b0, w1, b1, h1n, (c + 1) * SC, M, j * 64,
                   sh.m, tid);
          __syncthreads();
        }
      }
    }
    return;
  }

  // -------------------- RNN blocks (chunk c-1), R0-validated --------------
  if (c == 0) return;
  const int cc = c - 1;               // rnn chunk index
  const float* trans = (cc & 1) ? trans1 : trans0;
  const int s_base = cc * SC;
  const int wv = tid >> 6;            // 0..7
  const int lane = tid & 63;
  const int b = blockIdx.x;

  if (tid < 6) sh.r.flags[tid] = 0;
  if (tid == 6) sh.r.cons = 0;
  __syncthreads();

  const float* base = trans + (size_t)b * DS2;

  if (wv > 0) {
    if (wv <= 3) {
      // producer: steps s ≡ wv-1 (mod 3)  [R0-validated protocol]
      const int p = wv - 1;
      int prev = -1;
      for (int s = p; s < SC; s += 3) {
        while (s - __hip_atomic_load(&sh.r.cons, __ATOMIC_RELAXED,
                                     __HIP_MEMORY_SCOPE_WORKGROUP) > 5)
          __builtin_amdgcn_s_sleep(2);
        const int slot = s % 6;
        const float* g = base + (size_t)s * (32 * DS2) + 4 * lane;
        float* l = (float*)&sh.r.ring[slot][0][0];
#pragma unroll
        for (int q = 0; q < 16; ++q)
          gl2lds16(g + q * 256, l + q * 256);
        if (prev >= 0) {
          asm volatile("s_waitcnt vmcnt(16)" ::: "memory");
          __hip_atomic_store(&sh.r.flags[prev % 6], prev + 1, __ATOMIC_RELAXED,
                             __HIP_MEMORY_SCOPE_WORKGROUP);
        }
        prev = s;
      }
      if (prev >= 0) {
        asm volatile("s_waitcnt vmcnt(0)" ::: "memory");
        __hip_atomic_store(&sh.r.flags[prev % 6], prev + 1, __ATOMIC_RELAXED,
                           __HIP_MEMORY_SCOPE_WORKGROUP);
      }
    }
    // wv == 4..7: idle
  } else {
    // consumer: serial recurrence
    const int d = lane >> 4;
    const int cq = lane & 15;
    const bool d1 = (d & 1), d2 = (d & 2);
    const int pb = lane & 48;

    float4 hq;
    if (cc == 0) {
      hq = *(const float4*)(init_hidden + 4 * cq);
      float ss0 = row_sum16(hq.x * hq.x + hq.y * hq.y + hq.z * hq.z + hq.w * hq.w);
      float iv0 = 1.0f / fmaxf(sqrtf(ss0), 1e-12f);
      hq.x *= iv0; hq.y *= iv0; hq.z *= iv0; hq.w *= iv0;
    } else {
      hq = *(const float4*)(hstate + b * DS + 4 * cq);
    }
    float inv_prev = 1.0f;

    float* outp = out + ((size_t)b * S_ + s_base) * DS + 4 * cq;
    int fpre = -1;
    for (int s = 0; s < SC; ++s) {
      const int slot = s % 6;
      if (fpre < s + 1) {
        while (__hip_atomic_load(&sh.r.flags[slot], __ATOMIC_ACQUIRE,
                                 __HIP_MEMORY_SCOPE_WORKGROUP) < s + 1)
          __builtin_amdgcn_s_sleep(0);
      }
      fpre = __hip_atomic_load(&sh.r.flags[(s + 1) % 6], __ATOMIC_ACQUIRE,
                               __HIP_MEMORY_SCOPE_WORKGROUP);

      float hsel = d2 ? (d1 ? hq.w : hq.z) : (d1 ? hq.y : hq.x);
      float ax = 0.f, ay = 0.f, az = 0.f, aw = 0.f;
#pragma unroll
      for (int q = 0; q < 16; ++q) {
        float4 t4 = sh.r.ring[slot][q][lane];
        float hb = __shfl(hsel, pb + q, 64);
        ax += hb * t4.x; ay += hb * t4.y;
        az += hb * t4.z; aw += hb * t4.w;
      }
      __hip_atomic_store(&sh.r.cons, s + 1, __ATOMIC_RELAXED,
                         __HIP_MEMORY_SCOPE_WORKGROUP);

      ax += __shfl_xor(ax, 16, 64); ax += __shfl_xor(ax, 32, 64);
      ay += __shfl_xor(ay, 16, 64); ay += __shfl_xor(ay, 32, 64);
      az += __shfl_xor(az, 16, 64); az += __shfl_xor(az, 32, 64);
      aw += __shfl_xor(aw, 16, 64); aw += __shfl_xor(aw, 32, 64);
      hq.x = fmaxf(ax * inv_prev, 0.f);
      hq.y = fmaxf(ay * inv_prev, 0.f);
      hq.z = fmaxf(az * inv_prev, 0.f);
      hq.w = fmaxf(aw * inv_prev, 0.f);
      float ss = row_sum16(hq.x * hq.x + hq.y * hq.y + hq.z * hq.z + hq.w * hq.w);
      float inv = 1.0f / fmaxf(sqrtf(ss), 1e-12f);
      if (d == 0) {
        float4 o;
        o.x = hq.x * inv; o.y = hq.y * inv; o.z = hq.z * inv; o.w = hq.w * inv;
        *(float4*)(outp + (size_t)s * DS) = o;
      }
      inv_prev = inv;
    }
    if (d == 0) {
      float4 o;   // carry NORMALIZED state across chunks
      o.x = hq.x * inv_prev; o.y = hq.y * inv_prev;
      o.z = hq.z * inv_prev; o.w = hq.w * inv_prev;
      *(float4*)(hstate + b * DS + 4 * cq) = o;
    }
  }
}

// ---------------------------------------------------------------------------
extern "C" void kernel_launch(void* const* d_in, const int* in_sizes, int n_in,
                              void* d_out, int out_size, void* d_ws, size_t ws_size,
                              hipStream_t stream) {
  const float* actions     = (const float*)d_in[0];
  const float* w0          = (const float*)d_in[1];
  const float* b0          = (const float*)d_in[2];
  const float* w1          = (const float*)d_in[3];
  const float* b1          = (const float*)d_in[4];
  const float* w2          = (const float*)d_in[5];
  const float* b2          = (const float*)d_in[6];
  const float* init_hidden = (const float*)d_in[7];
  float* out = (float*)d_out;

  // largest chunk whose DOUBLE-buffered workspace fits
  int SC = 2048;
  while (SC > 4) {
    size_t need = 2 * ((size_t)SC * 32 * DS2 * 4 + (size_t)SC * 32 * DH * 4)
                + (size_t)B_ * DS * 4;
    if (need <= ws_size) break;
    SC >>= 1;
  }
  float* trans0 = (float*)d_ws;
  float* trans1 = trans0 + (size_t)SC * 32 * DS2;
  float* h1t0   = trans1 + (size_t)SC * 32 * DS2;
  float* h1t1   = h1t0 + (size_t)SC * 32 * DH;
  float* hstate = h1t1 + (size_t)SC * 32 * DH;

  const int M = SC * 32;
  const int nch = S_ / SC;

  // prime: mlp for chunk 0 -> h1t0
  hipLaunchKernelGGL(k_mlp01, dim3(M / 64), dim3(512), 0, stream,
                     actions, w0, b0, w1, b1, h1t0, 0, M);
  // pipelined combined launches
  for (int c = 0; c <= nch; ++c) {
    hipLaunchKernelGGL(k_comb, dim3(256), dim3(512), 0, stream,
                       actions, w0, b0, w1, b1, w2, b2, init_hidden,
                       trans0, trans1, h1t0, h1t1, hstate, out, c, SC, nch);
  }
}

// Round 4
// 1586.210 us; speedup vs baseline: 1.1059x; 1.1059x over previous
//
#include <hip/hip_runtime.h>

// Problem constants
#define B_ 32
#define S_ 2048
#define DA 32
#define DH 128
#define DS 64
#define DS2 4096
#define TKK 16

template <int CTRL>
__device__ __forceinline__ float dpp_add(float x) {
  int t = __builtin_amdgcn_update_dpp(0, __float_as_int(x), CTRL, 0xF, 0xF, true);
  return x + __int_as_float(t);
}
// sum over the 16 lanes of each row, result uniform within the row
__device__ __forceinline__ float row_sum16(float x) {
  x = dpp_add<0xB1>(x);
  x = dpp_add<0x4E>(x);
  x = dpp_add<0x141>(x);
  x = dpp_add<0x140>(x);
  return x;
}

// async global->LDS DMA, 16 B per lane (dest = wave-uniform base + lane*16)
__device__ __forceinline__ void gl2lds16(const float* g, float* l) {
  __builtin_amdgcn_global_load_lds(
      (const __attribute__((address_space(1))) void*)g,
      (__attribute__((address_space(3))) void*)l, 16, 0, 0);
}

// ---------------------------------------------------------------------------
// Shared-memory union. 512-thread blocks, 132 KB -> 1 block/CU (as before).
// GEMM: FULL-K A tile (128x128 = 64 KB) staged once per tile -> the whole
// K-loop runs BARRIER-FREE (R0-R3 showed ~50% of tile time was the 8
// per-stage barrier drains). B (w2) read direct from global (L1-resident).
// ---------------------------------------------------------------------------
struct SharedRnn {
  float4 ring[6][16][64];   // 96 KB
  int flags[6];
  int cons;
};
struct SharedGemm {
  float As[DH][128];        // 64 KB: full-K A tile (rows = k, cols = m)
  float4 part[256][17];     // 68 KB split-K combine buffer (padded rows)
};
struct SharedMlp {
  float a_t[DA][64];        // 8 KB
  float w0_l[DA][DH];       // 16 KB
  float h0t[DH][64];        // 32 KB
};
union SharedU {
  SharedRnn r;
  SharedGemm g;
  SharedMlp m;
};

// ---------------------------------------------------------------------------
// MLP tile, 512-thread version: 64 tokens -> h1t[f][tok] (transposed).
// ---------------------------------------------------------------------------
__device__ __forceinline__ void mlp_tile(
    const float* __restrict__ actions, const float* __restrict__ w0,
    const float* __restrict__ b0, const float* __restrict__ w1,
    const float* __restrict__ b1, float* __restrict__ h1t,
    int s_base, int M, int m0, SharedMlp& sm, int tid)
{
  {
    // 512 threads stage a_t in one pass: tok = tid>>3, kq = tid&7
    int tok = tid >> 3, kq = tid & 7;
    int tl = m0 + tok;
    int b = tl & 31, s = s_base + (tl >> 5);
    float4 v = *(const float4*)(actions + ((size_t)b * S_ + s) * DA + 4 * kq);
    sm.a_t[4 * kq + 0][tok] = v.x; sm.a_t[4 * kq + 1][tok] = v.y;
    sm.a_t[4 * kq + 2][tok] = v.z; sm.a_t[4 * kq + 3][tok] = v.w;
  }
#pragma unroll
  for (int q = 0; q < 2; ++q) {
    int g = tid + 512 * q;        // 1024 float4s of w0
    ((float4*)&sm.w0_l[0][0])[g] = ((const float4*)w0)[g];
  }
  __syncthreads();

  const int tm = tid & 15;        // token group: tokens 4*tm+mi
  const int tn = tid >> 4;        // 0..31: features 4*tn+ni

  float acc[4][4];
#pragma unroll
  for (int mi = 0; mi < 4; ++mi)
#pragma unroll
    for (int ni = 0; ni < 4; ++ni) acc[mi][ni] = 0.f;

#pragma unroll 4
  for (int k = 0; k < DA; ++k) {
    float4 a4 = *(const float4*)&sm.a_t[k][4 * tm];
    float4 w4 = *(const float4*)&sm.w0_l[k][4 * tn];
    float av[4] = {a4.x, a4.y, a4.z, a4.w};
    float wv[4] = {w4.x, w4.y, w4.z, w4.w};
#pragma unroll
    for (int mi = 0; mi < 4; ++mi)
#pragma unroll
      for (int ni = 0; ni < 4; ++ni) acc[mi][ni] += av[mi] * wv[ni];
  }
  {
    float4 b4 = *(const float4*)(b0 + 4 * tn);
    float bv[4] = {b4.x, b4.y, b4.z, b4.w};
#pragma unroll
    for (int mi = 0; mi < 4; ++mi)
#pragma unroll
      for (int ni = 0; ni < 4; ++ni)
        sm.h0t[4 * tn + ni][4 * tm + mi] = fmaxf(acc[mi][ni] + bv[ni], 0.f);
  }
  __syncthreads();

  float acc1[4][4];
#pragma unroll
  for (int mi = 0; mi < 4; ++mi)
#pragma unroll
    for (int ni = 0; ni < 4; ++ni) acc1[mi][ni] = 0.f;

#pragma unroll 4
  for (int k = 0; k < DH; ++k) {
    float4 h4 = *(const float4*)&sm.h0t[k][4 * tm];
    float4 w4 = *(const float4*)(w1 + (size_t)k * DH + 4 * tn);
    float av[4] = {h4.x, h4.y, h4.z, h4.w};
    float wv[4] = {w4.x, w4.y, w4.z, w4.w};
#pragma unroll
    for (int mi = 0; mi < 4; ++mi)
#pragma unroll
      for (int ni = 0; ni < 4; ++ni) acc1[mi][ni] += av[mi] * wv[ni];
  }
  {
    float4 b4 = *(const float4*)(b1 + 4 * tn);
    float bv[4] = {b4.x, b4.y, b4.z, b4.w};
#pragma unroll
    for (int ni = 0; ni < 4; ++ni) {
      float4 o;
      o.x = fmaxf(acc1[0][ni] + bv[ni], 0.f);
      o.y = fmaxf(acc1[1][ni] + bv[ni], 0.f);
      o.z = fmaxf(acc1[2][ni] + bv[ni], 0.f);
      o.w = fmaxf(acc1[3][ni] + bv[ni], 0.f);
      *(float4*)(h1t + (size_t)(4 * tn + ni) * M + m0 + 4 * tm) = o;
    }
  }
}

// ---------------------------------------------------------------------------
// Trans GEMM loop, 512-thread split-K, full-K A staging:
//  per tile: [K=64 compute, NO barriers] -> bar -> part-write || next-A DMA
//            -> bar -> combine+store (DMA in flight) -> vmcnt(0) -> bar
// 3 barriers/tile instead of 8 per-stage drains (R0-R3's invariant ~50% cost).
// ---------------------------------------------------------------------------
__device__ __forceinline__ void trans_loop(
    const float* __restrict__ h1t, const float* __restrict__ w2,
    const float* __restrict__ b2, float* __restrict__ trans,
    int M, int bi, SharedGemm& sg, int tid)
{
  const int w  = tid >> 6;     // 0..7
  const int lw = tid & 63;
  const int NJ = (M / 128) * (DS2 / 128);
  if (bi >= NJ) return;        // block-uniform

  // full-K A staging: wave w stages rows 16w .. 16w+15 (8 DMAs, 2 rows each)
  auto aloadF = [&](int j) {
    const int m0 = (j >> 5) * 128;
    const int rb = 16 * w;
    const int c4 = 4 * (lw & 31);
    const int ro = lw >> 5;
#pragma unroll
    for (int q = 0; q < 8; ++q) {
      const int kr = rb + 2 * q + ro;
      gl2lds16(h1t + (size_t)kr * M + m0 + c4, &sg.As[rb + 2 * q][0]);
    }
  };

  const int sub = tid & 255;
  const int khalf = tid >> 8;        // 0: k 0..63 / 1: k 64..127
  const int mg = sub >> 4;
  const int ng = sub & 15;
  const int kb = 64 * khalf;

  aloadF(bi);
  asm volatile("s_waitcnt vmcnt(0)" ::: "memory");
  __syncthreads();

  for (int j = bi; j < NJ; j += 224) {
    const int m0 = (j >> 5) * 128, n0 = (j & 31) * 128;

    float acc[8][8];
#pragma unroll
    for (int mi = 0; mi < 8; ++mi)
#pragma unroll
      for (int ni = 0; ni < 8; ++ni) acc[mi][ni] = 0.f;

    const float* w2p = w2 + (size_t)kb * DS2 + n0 + 4 * ng;
#pragma unroll 4
    for (int k8 = 0; k8 < 64; ++k8) {
      float4 b0v = *(const float4*)(w2p + (size_t)k8 * DS2);
      float4 b1v = *(const float4*)(w2p + (size_t)k8 * DS2 + 64);
      float4 a0 = *(const float4*)&sg.As[kb + k8][8 * mg];
      float4 a1 = *(const float4*)&sg.As[kb + k8][8 * mg + 4];
      float av[8] = {a0.x, a0.y, a0.z, a0.w, a1.x, a1.y, a1.z, a1.w};
      float bv[8] = {b0v.x, b0v.y, b0v.z, b0v.w, b1v.x, b1v.y, b1v.z, b1v.w};
#pragma unroll
      for (int mi = 0; mi < 8; ++mi)
#pragma unroll
        for (int ni = 0; ni < 8; ++ni) acc[mi][ni] += av[mi] * bv[ni];
    }
    __syncthreads();                       // (B) all As reads complete

    if (khalf) {
#pragma unroll
      for (int mi = 0; mi < 8; ++mi) {
        sg.part[sub][2 * mi] =
            make_float4(acc[mi][0], acc[mi][1], acc[mi][2], acc[mi][3]);
        sg.part[sub][2 * mi + 1] =
            make_float4(acc[mi][4], acc[mi][5], acc[mi][6], acc[mi][7]);
      }
    }
    if (j + 224 < NJ) aloadF(j + 224);     // next-tile A DMA overlaps epilogue
    __syncthreads();                       // (C) part visible

    if (!khalf) {
      float4 bb0 = *(const float4*)(b2 + n0 + 4 * ng);
      float4 bb1 = *(const float4*)(b2 + n0 + 64 + 4 * ng);
      float bv[8] = {bb0.x, bb0.y, bb0.z, bb0.w, bb1.x, bb1.y, bb1.z, bb1.w};
#pragma unroll
      for (int mi = 0; mi < 8; ++mi) {
        float4 p0 = sg.part[sub][2 * mi];
        float4 p1 = sg.part[sub][2 * mi + 1];
        float pv[8] = {p0.x, p0.y, p0.z, p0.w, p1.x, p1.y, p1.z, p1.w};
        float* dst = trans + (size_t)(m0 + 8 * mg + mi) * DS2 + n0;
#pragma unroll
        for (int q = 0; q < 2; ++q) {
          float4 o;
          o.x = acc[mi][4 * q + 0] + pv[4 * q + 0] + bv[4 * q + 0];
          o.y = acc[mi][4 * q + 1] + pv[4 * q + 1] + bv[4 * q + 1];
          o.z = acc[mi][4 * q + 2] + pv[4 * q + 2] + bv[4 * q + 2];
          o.w = acc[mi][4 * q + 3] + pv[4 * q + 3] + bv[4 * q + 3];
          *(float4*)(dst + 64 * q + 4 * ng) = o;
        }
      }
    }
    asm volatile("s_waitcnt vmcnt(0)" ::: "memory");  // own DMAs landed
    __syncthreads();                       // (D) As fully staged for next tile
  }
}

// ---------------------------------------------------------------------------
// Standalone MLP kernel (chunk 0 priming)
// ---------------------------------------------------------------------------
__global__ __launch_bounds__(512) void k_mlp01(
    const float* __restrict__ actions, const float* __restrict__ w0,
    const float* __restrict__ b0, const float* __restrict__ w1,
    const float* __restrict__ b1, float* __restrict__ h1t,
    int s_base, int M)
{
  __shared__ SharedMlp sm;
  mlp_tile(actions, w0, b0, w1, b1, h1t, s_base, M, blockIdx.x * 64, sm,
           threadIdx.x);
}

// ---------------------------------------------------------------------------
// Combined pipelined kernel, launch index c = 0..nch:
//  blocks 0..31  : rnn for chunk c-1 (if c>0), reading trans[(c-1)%2]
//  blocks 32..255: trans tiles for chunk c (if c<nch): h1t[c%2] -> trans[c%2],
//                  then mlp tiles for chunk c+1 (if c+1<nch) -> h1t[(c+1)%2]
// ALL dependencies are cross-launch (stream-ordered); no cross-block sync.
// RNN keeps the R0-validated protocol: consumer = wave 0, producers =
// waves 1..3 (stride 3), waves 4..7 idle.
// ---------------------------------------------------------------------------
__global__ __launch_bounds__(512, 1) void k_comb(
    const float* __restrict__ actions, const float* __restrict__ w0,
    const float* __restrict__ b0, const float* __restrict__ w1,
    const float* __restrict__ b1, const float* __restrict__ w2,
    const float* __restrict__ b2, const float* __restrict__ init_hidden,
    float* __restrict__ trans0, float* __restrict__ trans1,
    float* __restrict__ h1t0, float* __restrict__ h1t1,
    float* __restrict__ hstate, float* __restrict__ out,
    int c, int SC, int nch)
{
  __shared__ SharedU sh;
  const int tid = threadIdx.x;
  const int M = SC * 32;

  if (blockIdx.x >= 32) {
    // -------------------- GEMM blocks --------------------
    const int bi = blockIdx.x - 32;   // 0..223
    if (c < nch) {
      const float* h1t = (c & 1) ? h1t1 : h1t0;
      float* trans = (c & 1) ? trans1 : trans0;
      trans_loop(h1t, w2, b2, trans, M, bi, sh.g, tid);
      if (c + 1 < nch) {
        __syncthreads();
        float* h1n = ((c + 1) & 1) ? h1t1 : h1t0;
        for (int j = bi; j < M / 64; j += 224) {
          mlp_tile(actions, w0, b0, w1, b1, h1n, (c + 1) * SC, M, j * 64,
                   sh.m, tid);
          __syncthreads();
        }
      }
    }
    return;
  }

  // -------------------- RNN blocks (chunk c-1), R0-validated --------------
  if (c == 0) return;
  const int cc = c - 1;               // rnn chunk index
  const float* trans = (cc & 1) ? trans1 : trans0;
  const int s_base = cc * SC;
  const int wv = tid >> 6;            // 0..7
  const int lane = tid & 63;
  const int b = blockIdx.x;

  if (tid < 6) sh.r.flags[tid] = 0;
  if (tid == 6) sh.r.cons = 0;
  __syncthreads();

  const float* base = trans + (size_t)b * DS2;

  if (wv > 0) {
    if (wv <= 3) {
      // producer: steps s ≡ wv-1 (mod 3)  [R0-validated protocol]
      const int p = wv - 1;
      int prev = -1;
      for (int s = p; s < SC; s += 3) {
        while (s - __hip_atomic_load(&sh.r.cons, __ATOMIC_RELAXED,
                                     __HIP_MEMORY_SCOPE_WORKGROUP) > 5)
          __builtin_amdgcn_s_sleep(2);
        const int slot = s % 6;
        const float* g = base + (size_t)s * (32 * DS2) + 4 * lane;
        float* l = (float*)&sh.r.ring[slot][0][0];
#pragma unroll
        for (int q = 0; q < 16; ++q)
          gl2lds16(g + q * 256, l + q * 256);
        if (prev >= 0) {
          asm volatile("s_waitcnt vmcnt(16)" ::: "memory");
          __hip_atomic_store(&sh.r.flags[prev % 6], prev + 1, __ATOMIC_RELAXED,
                             __HIP_MEMORY_SCOPE_WORKGROUP);
        }
        prev = s;
      }
      if (prev >= 0) {
        asm volatile("s_waitcnt vmcnt(0)" ::: "memory");
        __hip_atomic_store(&sh.r.flags[prev % 6], prev + 1, __ATOMIC_RELAXED,
                           __HIP_MEMORY_SCOPE_WORKGROUP);
      }
    }
    // wv == 4..7: idle
  } else {
    // consumer: serial recurrence
    const int d = lane >> 4;
    const int cq = lane & 15;
    const bool d1 = (d & 1), d2 = (d & 2);
    const int pb = lane & 48;

    float4 hq;
    if (cc == 0) {
      hq = *(const float4*)(init_hidden + 4 * cq);
      float ss0 = row_sum16(hq.x * hq.x + hq.y * hq.y + hq.z * hq.z + hq.w * hq.w);
      float iv0 = 1.0f / fmaxf(sqrtf(ss0), 1e-12f);
      hq.x *= iv0; hq.y *= iv0; hq.z *= iv0; hq.w *= iv0;
    } else {
      hq = *(const float4*)(hstate + b * DS + 4 * cq);
    }
    float inv_prev = 1.0f;

    float* outp = out + ((size_t)b * S_ + s_base) * DS + 4 * cq;
    int fpre = -1;
    for (int s = 0; s < SC; ++s) {
      const int slot = s % 6;
      if (fpre < s + 1) {
        while (__hip_atomic_load(&sh.r.flags[slot], __ATOMIC_ACQUIRE,
                                 __HIP_MEMORY_SCOPE_WORKGROUP) < s + 1)
          __builtin_amdgcn_s_sleep(0);
      }
      fpre = __hip_atomic_load(&sh.r.flags[(s + 1) % 6], __ATOMIC_ACQUIRE,
                               __HIP_MEMORY_SCOPE_WORKGROUP);

      float hsel = d2 ? (d1 ? hq.w : hq.z) : (d1 ? hq.y : hq.x);
      float ax = 0.f, ay = 0.f, az = 0.f, aw = 0.f;
#pragma unroll
      for (int q = 0; q < 16; ++q) {
        float4 t4 = sh.r.ring[slot][q][lane];
        float hb = __shfl(hsel, pb + q, 64);
        ax += hb * t4.x; ay += hb * t4.y;
        az += hb * t4.z; aw += hb * t4.w;
      }
      __hip_atomic_store(&sh.r.cons, s + 1, __ATOMIC_RELAXED,
                         __HIP_MEMORY_SCOPE_WORKGROUP);

      ax += __shfl_xor(ax, 16, 64); ax += __shfl_xor(ax, 32, 64);
      ay += __shfl_xor(ay, 16, 64); ay += __shfl_xor(ay, 32, 64);
      az += __shfl_xor(az, 16, 64); az += __shfl_xor(az, 32, 64);
      aw += __shfl_xor(aw, 16, 64); aw += __shfl_xor(aw, 32, 64);
      hq.x = fmaxf(ax * inv_prev, 0.f);
      hq.y = fmaxf(ay * inv_prev, 0.f);
      hq.z = fmaxf(az * inv_prev, 0.f);
      hq.w = fmaxf(aw * inv_prev, 0.f);
      float ss = row_sum16(hq.x * hq.x + hq.y * hq.y + hq.z * hq.z + hq.w * hq.w);
      float inv = 1.0f / fmaxf(sqrtf(ss), 1e-12f);
      if (d == 0) {
        float4 o;
        o.x = hq.x * inv; o.y = hq.y * inv; o.z = hq.z * inv; o.w = hq.w * inv;
        *(float4*)(outp + (size_t)s * DS) = o;
      }
      inv_prev = inv;
    }
    if (d == 0) {
      float4 o;   // carry NORMALIZED state across chunks
      o.x = hq.x * inv_prev; o.y = hq.y * inv_prev;
      o.z = hq.z * inv_prev; o.w = hq.w * inv_prev;
      *(float4*)(hstate + b * DS + 4 * cq) = o;
    }
  }
}

// ---------------------------------------------------------------------------
extern "C" void kernel_launch(void* const* d_in, const int* in_sizes, int n_in,
                              void* d_out, int out_size, void* d_ws, size_t ws_size,
                              hipStream_t stream) {
  const float* actions     = (const float*)d_in[0];
  const float* w0          = (const float*)d_in[1];
  const float* b0          = (const float*)d_in[2];
  const float* w1          = (const float*)d_in[3];
  const float* b1          = (const float*)d_in[4];
  const float* w2          = (const float*)d_in[5];
  const float* b2          = (const float*)d_in[6];
  const float* init_hidden = (const float*)d_in[7];
  float* out = (float*)d_out;

  // largest chunk whose DOUBLE-buffered workspace fits
  int SC = 2048;
  while (SC > 4) {
    size_t need = 2 * ((size_t)SC * 32 * DS2 * 4 + (size_t)SC * 32 * DH * 4)
                + (size_t)B_ * DS * 4;
    if (need <= ws_size) break;
    SC >>= 1;
  }
  float* trans0 = (float*)d_ws;
  float* trans1 = trans0 + (size_t)SC * 32 * DS2;
  float* h1t0   = trans1 + (size_t)SC * 32 * DS2;
  float* h1t1   = h1t0 + (size_t)SC * 32 * DH;
  float* hstate = h1t1 + (size_t)SC * 32 * DH;

  const int M = SC * 32;
  const int nch = S_ / SC;

  // prime: mlp for chunk 0 -> h1t0
  hipLaunchKernelGGL(k_mlp01, dim3(M / 64), dim3(512), 0, stream,
                     actions, w0, b0, w1, b1, h1t0, 0, M);
  // pipelined combined launches
  for (int c = 0; c <= nch; ++c) {
    hipLaunchKernelGGL(k_comb, dim3(256), dim3(512), 0, stream,
                       actions, w0, b0, w1, b1, w2, b2, init_hidden,
                       trans0, trans1, h1t0, h1t1, hstate, out, c, SC, nch);
  }
}

// Round 5
// 1585.690 us; speedup vs baseline: 1.1063x; 1.0003x over previous
//
#include <hip/hip_runtime.h>

// Problem constants
#define B_ 32
#define S_ 2048
#define DA 32
#define DH 128
#define DS 64
#define DS2 4096
#define TKK 16

template <int CTRL>
__device__ __forceinline__ float dpp_add(float x) {
  int t = __builtin_amdgcn_update_dpp(0, __float_as_int(x), CTRL, 0xF, 0xF, true);
  return x + __int_as_float(t);
}
// sum over the 16 lanes of each row, result uniform within the row
__device__ __forceinline__ float row_sum16(float x) {
  x = dpp_add<0xB1>(x);
  x = dpp_add<0x4E>(x);
  x = dpp_add<0x141>(x);
  x = dpp_add<0x140>(x);
  return x;
}

// async global->LDS DMA, 16 B per lane (dest = wave-uniform base + lane*16)
__device__ __forceinline__ void gl2lds16(const float* g, float* l) {
  __builtin_amdgcn_global_load_lds(
      (const __attribute__((address_space(1))) void*)g,
      (__attribute__((address_space(3))) void*)l, 16, 0, 0);
}

// ---------------------------------------------------------------------------
// Shared-memory union. 512-thread blocks, 132 KB -> 1 block/CU.
// GEMM: FULL-K A tile (128x128 = 64 KB) staged once per tile; K-loop is
// barrier-free AND explicitly software-pipelined 2-deep (R4's VGPR=88 showed
// the compiler allocated zero prefetch depth -> ~200cy load-latency stall per
// k-step, VALUBusy pinned at ~35%). B (w2) read direct from global (L2).
// ---------------------------------------------------------------------------
struct SharedRnn {
  float4 ring[6][16][64];   // 96 KB
  int flags[6];
  int cons;
};
struct SharedGemm {
  float As[DH][128];        // 64 KB: full-K A tile (rows = k, cols = m)
  float4 part[256][17];     // 68 KB split-K combine buffer (padded rows)
};
struct SharedMlp {
  float a_t[DA][64];        // 8 KB
  float w0_l[DA][DH];       // 16 KB
  float h0t[DH][64];        // 32 KB
};
union SharedU {
  SharedRnn r;
  SharedGemm g;
  SharedMlp m;
};

// ---------------------------------------------------------------------------
// MLP tile, 512-thread version: 64 tokens -> h1t[f][tok] (transposed).
// ---------------------------------------------------------------------------
__device__ __forceinline__ void mlp_tile(
    const float* __restrict__ actions, const float* __restrict__ w0,
    const float* __restrict__ b0, const float* __restrict__ w1,
    const float* __restrict__ b1, float* __restrict__ h1t,
    int s_base, int M, int m0, SharedMlp& sm, int tid)
{
  {
    // 512 threads stage a_t in one pass: tok = tid>>3, kq = tid&7
    int tok = tid >> 3, kq = tid & 7;
    int tl = m0 + tok;
    int b = tl & 31, s = s_base + (tl >> 5);
    float4 v = *(const float4*)(actions + ((size_t)b * S_ + s) * DA + 4 * kq);
    sm.a_t[4 * kq + 0][tok] = v.x; sm.a_t[4 * kq + 1][tok] = v.y;
    sm.a_t[4 * kq + 2][tok] = v.z; sm.a_t[4 * kq + 3][tok] = v.w;
  }
#pragma unroll
  for (int q = 0; q < 2; ++q) {
    int g = tid + 512 * q;        // 1024 float4s of w0
    ((float4*)&sm.w0_l[0][0])[g] = ((const float4*)w0)[g];
  }
  __syncthreads();

  const int tm = tid & 15;        // token group: tokens 4*tm+mi
  const int tn = tid >> 4;        // 0..31: features 4*tn+ni

  float acc[4][4];
#pragma unroll
  for (int mi = 0; mi < 4; ++mi)
#pragma unroll
    for (int ni = 0; ni < 4; ++ni) acc[mi][ni] = 0.f;

#pragma unroll 4
  for (int k = 0; k < DA; ++k) {
    float4 a4 = *(const float4*)&sm.a_t[k][4 * tm];
    float4 w4 = *(const float4*)&sm.w0_l[k][4 * tn];
    float av[4] = {a4.x, a4.y, a4.z, a4.w};
    float wv[4] = {w4.x, w4.y, w4.z, w4.w};
#pragma unroll
    for (int mi = 0; mi < 4; ++mi)
#pragma unroll
      for (int ni = 0; ni < 4; ++ni) acc[mi][ni] += av[mi] * wv[ni];
  }
  {
    float4 b4 = *(const float4*)(b0 + 4 * tn);
    float bv[4] = {b4.x, b4.y, b4.z, b4.w};
#pragma unroll
    for (int mi = 0; mi < 4; ++mi)
#pragma unroll
      for (int ni = 0; ni < 4; ++ni)
        sm.h0t[4 * tn + ni][4 * tm + mi] = fmaxf(acc[mi][ni] + bv[ni], 0.f);
  }
  __syncthreads();

  float acc1[4][4];
#pragma unroll
  for (int mi = 0; mi < 4; ++mi)
#pragma unroll
    for (int ni = 0; ni < 4; ++ni) acc1[mi][ni] = 0.f;

#pragma unroll 4
  for (int k = 0; k < DH; ++k) {
    float4 h4 = *(const float4*)&sm.h0t[k][4 * tm];
    float4 w4 = *(const float4*)(w1 + (size_t)k * DH + 4 * tn);
    float av[4] = {h4.x, h4.y, h4.z, h4.w};
    float wv[4] = {w4.x, w4.y, w4.z, w4.w};
#pragma unroll
    for (int mi = 0; mi < 4; ++mi)
#pragma unroll
      for (int ni = 0; ni < 4; ++ni) acc1[mi][ni] += av[mi] * wv[ni];
  }
  {
    float4 b4 = *(const float4*)(b1 + 4 * tn);
    float bv[4] = {b4.x, b4.y, b4.z, b4.w};
#pragma unroll
    for (int ni = 0; ni < 4; ++ni) {
      float4 o;
      o.x = fmaxf(acc1[0][ni] + bv[ni], 0.f);
      o.y = fmaxf(acc1[1][ni] + bv[ni], 0.f);
      o.z = fmaxf(acc1[2][ni] + bv[ni], 0.f);
      o.w = fmaxf(acc1[3][ni] + bv[ni], 0.f);
      *(float4*)(h1t + (size_t)(4 * tn + ni) * M + m0 + 4 * tm) = o;
    }
  }
}

// ---------------------------------------------------------------------------
// Trans GEMM loop, 512-thread split-K, full-K A staging, software-pipelined
// K-loop (2-deep explicit prefetch: operands for k+2/k+3 are loaded into
// named rotating register sets BEFORE the FMA blocks of k/k+1, giving ~256cy
// of latency cover per load -- the compiler alone allocated none, VGPR=88).
// ---------------------------------------------------------------------------
__device__ __forceinline__ void trans_loop(
    const float* __restrict__ h1t, const float* __restrict__ w2,
    const float* __restrict__ b2, float* __restrict__ trans,
    int M, int bi, SharedGemm& sg, int tid)
{
  const int w  = tid >> 6;     // 0..7
  const int lw = tid & 63;
  const int NJ = (M / 128) * (DS2 / 128);
  if (bi >= NJ) return;        // block-uniform

  // full-K A staging: wave w stages rows 16w .. 16w+15 (8 DMAs, 2 rows each)
  auto aloadF = [&](int j) {
    const int m0 = (j >> 5) * 128;
    const int rb = 16 * w;
    const int c4 = 4 * (lw & 31);
    const int ro = lw >> 5;
#pragma unroll
    for (int q = 0; q < 8; ++q) {
      const int kr = rb + 2 * q + ro;
      gl2lds16(h1t + (size_t)kr * M + m0 + c4, &sg.As[rb + 2 * q][0]);
    }
  };

  const int sub = tid & 255;
  const int khalf = tid >> 8;        // 0: k 0..63 / 1: k 64..127
  const int mg = sub >> 4;
  const int ng = sub & 15;
  const int kb = 64 * khalf;

  aloadF(bi);
  asm volatile("s_waitcnt vmcnt(0)" ::: "memory");
  __syncthreads();

  for (int j = bi; j < NJ; j += 224) {
    const int m0 = (j >> 5) * 128, n0 = (j & 31) * 128;

    float acc[8][8];
#pragma unroll
    for (int mi = 0; mi < 8; ++mi)
#pragma unroll
      for (int ni = 0; ni < 8; ++ni) acc[mi][ni] = 0.f;

    const float* w2p = w2 + (size_t)kb * DS2 + n0 + 4 * ng;
    const float* asp = &sg.As[kb][0];          // row stride = 128 floats

    auto fma8 = [&](const float4& A0, const float4& A1,
                    const float4& B0, const float4& B1) {
      float av[8] = {A0.x, A0.y, A0.z, A0.w, A1.x, A1.y, A1.z, A1.w};
      float bv[8] = {B0.x, B0.y, B0.z, B0.w, B1.x, B1.y, B1.z, B1.w};
#pragma unroll
      for (int mi = 0; mi < 8; ++mi)
#pragma unroll
        for (int ni = 0; ni < 8; ++ni) acc[mi][ni] += av[mi] * bv[ni];
    };

    // prologue: preload k=0 (set a) and k=1 (set b)
    float4 Aa0 = *(const float4*)(asp + 0 * 128 + 8 * mg);
    float4 Aa1 = *(const float4*)(asp + 0 * 128 + 8 * mg + 4);
    float4 Ba0 = *(const float4*)(w2p + (size_t)0 * DS2);
    float4 Ba1 = *(const float4*)(w2p + (size_t)0 * DS2 + 64);
    float4 Ab0 = *(const float4*)(asp + 1 * 128 + 8 * mg);
    float4 Ab1 = *(const float4*)(asp + 1 * 128 + 8 * mg + 4);
    float4 Bb0 = *(const float4*)(w2p + (size_t)1 * DS2);
    float4 Bb1 = *(const float4*)(w2p + (size_t)1 * DS2 + 64);

#pragma unroll 4
    for (int k8 = 0; k8 < 62; k8 += 2) {
      // prefetch k8+2 before consuming set a
      float4 nA0 = *(const float4*)(asp + (k8 + 2) * 128 + 8 * mg);
      float4 nA1 = *(const float4*)(asp + (k8 + 2) * 128 + 8 * mg + 4);
      float4 nB0 = *(const float4*)(w2p + (size_t)(k8 + 2) * DS2);
      float4 nB1 = *(const float4*)(w2p + (size_t)(k8 + 2) * DS2 + 64);
      fma8(Aa0, Aa1, Ba0, Ba1);
      // prefetch k8+3 before consuming set b
      float4 mA0 = *(const float4*)(asp + (k8 + 3) * 128 + 8 * mg);
      float4 mA1 = *(const float4*)(asp + (k8 + 3) * 128 + 8 * mg + 4);
      float4 mB0 = *(const float4*)(w2p + (size_t)(k8 + 3) * DS2);
      float4 mB1 = *(const float4*)(w2p + (size_t)(k8 + 3) * DS2 + 64);
      fma8(Ab0, Ab1, Bb0, Bb1);
      Aa0 = nA0; Aa1 = nA1; Ba0 = nB0; Ba1 = nB1;
      Ab0 = mA0; Ab1 = mA1; Bb0 = mB0; Bb1 = mB1;
    }
    fma8(Aa0, Aa1, Ba0, Ba1);   // k = 62
    fma8(Ab0, Ab1, Bb0, Bb1);   // k = 63

    __syncthreads();                       // (B) all As reads complete

    if (khalf) {
#pragma unroll
      for (int mi = 0; mi < 8; ++mi) {
        sg.part[sub][2 * mi] =
            make_float4(acc[mi][0], acc[mi][1], acc[mi][2], acc[mi][3]);
        sg.part[sub][2 * mi + 1] =
            make_float4(acc[mi][4], acc[mi][5], acc[mi][6], acc[mi][7]);
      }
    }
    if (j + 224 < NJ) aloadF(j + 224);     // next-tile A DMA overlaps epilogue
    __syncthreads();                       // (C) part visible

    if (!khalf) {
      float4 bb0 = *(const float4*)(b2 + n0 + 4 * ng);
      float4 bb1 = *(const float4*)(b2 + n0 + 64 + 4 * ng);
      float bv[8] = {bb0.x, bb0.y, bb0.z, bb0.w, bb1.x, bb1.y, bb1.z, bb1.w};
#pragma unroll
      for (int mi = 0; mi < 8; ++mi) {
        float4 p0 = sg.part[sub][2 * mi];
        float4 p1 = sg.part[sub][2 * mi + 1];
        float pv[8] = {p0.x, p0.y, p0.z, p0.w, p1.x, p1.y, p1.z, p1.w};
        float* dst = trans + (size_t)(m0 + 8 * mg + mi) * DS2 + n0;
#pragma unroll
        for (int q = 0; q < 2; ++q) {
          float4 o;
          o.x = acc[mi][4 * q + 0] + pv[4 * q + 0] + bv[4 * q + 0];
          o.y = acc[mi][4 * q + 1] + pv[4 * q + 1] + bv[4 * q + 1];
          o.z = acc[mi][4 * q + 2] + pv[4 * q + 2] + bv[4 * q + 2];
          o.w = acc[mi][4 * q + 3] + pv[4 * q + 3] + bv[4 * q + 3];
          *(float4*)(dst + 64 * q + 4 * ng) = o;
        }
      }
    }
    asm volatile("s_waitcnt vmcnt(0)" ::: "memory");  // own DMAs landed
    __syncthreads();                       // (D) As fully staged for next tile
  }
}

// ---------------------------------------------------------------------------
// Standalone MLP kernel (chunk 0 priming)
// ---------------------------------------------------------------------------
__global__ __launch_bounds__(512) void k_mlp01(
    const float* __restrict__ actions, const float* __restrict__ w0,
    const float* __restrict__ b0, const float* __restrict__ w1,
    const float* __restrict__ b1, float* __restrict__ h1t,
    int s_base, int M)
{
  __shared__ SharedMlp sm;
  mlp_tile(actions, w0, b0, w1, b1, h1t, s_base, M, blockIdx.x * 64, sm,
           threadIdx.x);
}

// ---------------------------------------------------------------------------
// Combined pipelined kernel, launch index c = 0..nch:
//  blocks 0..31  : rnn for chunk c-1 (if c>0), reading trans[(c-1)%2]
//  blocks 32..255: trans tiles for chunk c (if c<nch): h1t[c%2] -> trans[c%2],
//                  then mlp tiles for chunk c+1 (if c+1<nch) -> h1t[(c+1)%2]
// ALL dependencies are cross-launch (stream-ordered); no cross-block sync.
// RNN keeps the R0-validated protocol: consumer = wave 0, producers =
// waves 1..3 (stride 3), waves 4..7 idle.
// ---------------------------------------------------------------------------
__global__ __launch_bounds__(512, 1) void k_comb(
    const float* __restrict__ actions, const float* __restrict__ w0,
    const float* __restrict__ b0, const float* __restrict__ w1,
    const float* __restrict__ b1, const float* __restrict__ w2,
    const float* __restrict__ b2, const float* __restrict__ init_hidden,
    float* __restrict__ trans0, float* __restrict__ trans1,
    float* __restrict__ h1t0, float* __restrict__ h1t1,
    float* __restrict__ hstate, float* __restrict__ out,
    int c, int SC, int nch)
{
  __shared__ SharedU sh;
  const int tid = threadIdx.x;
  const int M = SC * 32;

  if (blockIdx.x >= 32) {
    // -------------------- GEMM blocks --------------------
    const int bi = blockIdx.x - 32;   // 0..223
    if (c < nch) {
      const float* h1t = (c & 1) ? h1t1 : h1t0;
      float* trans = (c & 1) ? trans1 : trans0;
      trans_loop(h1t, w2, b2, trans, M, bi, sh.g, tid);
      if (c + 1 < nch) {
        __syncthreads();
        float* h1n = ((c + 1) & 1) ? h1t1 : h1t0;
        for (int j = bi; j < M / 64; j += 224) {
          mlp_tile(actions, w0, b0, w1, b1, h1n, (c + 1) * SC, M, j * 64,
                   sh.m, tid);
          __syncthreads();
        }
      }
    }
    return;
  }

  // -------------------- RNN blocks (chunk c-1), R0-validated --------------
  if (c == 0) return;
  const int cc = c - 1;               // rnn chunk index
  const float* trans = (cc & 1) ? trans1 : trans0;
  const int s_base = cc * SC;
  const int wv = tid >> 6;            // 0..7
  const int lane = tid & 63;
  const int b = blockIdx.x;

  if (tid < 6) sh.r.flags[tid] = 0;
  if (tid == 6) sh.r.cons = 0;
  __syncthreads();

  const float* base = trans + (size_t)b * DS2;

  if (wv > 0) {
    if (wv <= 3) {
      // producer: steps s ≡ wv-1 (mod 3)  [R0-validated protocol]
      const int p = wv - 1;
      int prev = -1;
      for (int s = p; s < SC; s += 3) {
        while (s - __hip_atomic_load(&sh.r.cons, __ATOMIC_RELAXED,
                                     __HIP_MEMORY_SCOPE_WORKGROUP) > 5)
          __builtin_amdgcn_s_sleep(2);
        const int slot = s % 6;
        const float* g = base + (size_t)s * (32 * DS2) + 4 * lane;
        float* l = (float*)&sh.r.ring[slot][0][0];
#pragma unroll
        for (int q = 0; q < 16; ++q)
          gl2lds16(g + q * 256, l + q * 256);
        if (prev >= 0) {
          asm volatile("s_waitcnt vmcnt(16)" ::: "memory");
          __hip_atomic_store(&sh.r.flags[prev % 6], prev + 1, __ATOMIC_RELAXED,
                             __HIP_MEMORY_SCOPE_WORKGROUP);
        }
        prev = s;
      }
      if (prev >= 0) {
        asm volatile("s_waitcnt vmcnt(0)" ::: "memory");
        __hip_atomic_store(&sh.r.flags[prev % 6], prev + 1, __ATOMIC_RELAXED,
                           __HIP_MEMORY_SCOPE_WORKGROUP);
      }
    }
    // wv == 4..7: idle
  } else {
    // consumer: serial recurrence
    const int d = lane >> 4;
    const int cq = lane & 15;
    const bool d1 = (d & 1), d2 = (d & 2);
    const int pb = lane & 48;

    float4 hq;
    if (cc == 0) {
      hq = *(const float4*)(init_hidden + 4 * cq);
      float ss0 = row_sum16(hq.x * hq.x + hq.y * hq.y + hq.z * hq.z + hq.w * hq.w);
      float iv0 = 1.0f / fmaxf(sqrtf(ss0), 1e-12f);
      hq.x *= iv0; hq.y *= iv0; hq.z *= iv0; hq.w *= iv0;
    } else {
      hq = *(const float4*)(hstate + b * DS + 4 * cq);
    }
    float inv_prev = 1.0f;

    float* outp = out + ((size_t)b * S_ + s_base) * DS + 4 * cq;
    int fpre = -1;
    for (int s = 0; s < SC; ++s) {
      const int slot = s % 6;
      if (fpre < s + 1) {
        while (__hip_atomic_load(&sh.r.flags[slot], __ATOMIC_ACQUIRE,
                                 __HIP_MEMORY_SCOPE_WORKGROUP) < s + 1)
          __builtin_amdgcn_s_sleep(0);
      }
      fpre = __hip_atomic_load(&sh.r.flags[(s + 1) % 6], __ATOMIC_ACQUIRE,
                               __HIP_MEMORY_SCOPE_WORKGROUP);

      float hsel = d2 ? (d1 ? hq.w : hq.z) : (d1 ? hq.y : hq.x);
      float ax = 0.f, ay = 0.f, az = 0.f, aw = 0.f;
#pragma unroll
      for (int q = 0; q < 16; ++q) {
        float4 t4 = sh.r.ring[slot][q][lane];
        float hb = __shfl(hsel, pb + q, 64);
        ax += hb * t4.x; ay += hb * t4.y;
        az += hb * t4.z; aw += hb * t4.w;
      }
      __hip_atomic_store(&sh.r.cons, s + 1, __ATOMIC_RELAXED,
                         __HIP_MEMORY_SCOPE_WORKGROUP);

      ax += __shfl_xor(ax, 16, 64); ax += __shfl_xor(ax, 32, 64);
      ay += __shfl_xor(ay, 16, 64); ay += __shfl_xor(ay, 32, 64);
      az += __shfl_xor(az, 16, 64); az += __shfl_xor(az, 32, 64);
      aw += __shfl_xor(aw, 16, 64); aw += __shfl_xor(aw, 32, 64);
      hq.x = fmaxf(ax * inv_prev, 0.f);
      hq.y = fmaxf(ay * inv_prev, 0.f);
      hq.z = fmaxf(az * inv_prev, 0.f);
      hq.w = fmaxf(aw * inv_prev, 0.f);
      float ss = row_sum16(hq.x * hq.x + hq.y * hq.y + hq.z * hq.z + hq.w * hq.w);
      float inv = 1.0f / fmaxf(sqrtf(ss), 1e-12f);
      if (d == 0) {
        float4 o;
        o.x = hq.x * inv; o.y = hq.y * inv; o.z = hq.z * inv; o.w = hq.w * inv;
        *(float4*)(outp + (size_t)s * DS) = o;
      }
      inv_prev = inv;
    }
    if (d == 0) {
      float4 o;   // carry NORMALIZED state across chunks
      o.x = hq.x * inv_prev; o.y = hq.y * inv_prev;
      o.z = hq.z * inv_prev; o.w = hq.w * inv_prev;
      *(float4*)(hstate + b * DS + 4 * cq) = o;
    }
  }
}

// ---------------------------------------------------------------------------
extern "C" void kernel_launch(void* const* d_in, const int* in_sizes, int n_in,
                              void* d_out, int out_size, void* d_ws, size_t ws_size,
                              hipStream_t stream) {
  const float* actions     = (const float*)d_in[0];
  const float* w0          = (const float*)d_in[1];
  const float* b0          = (const float*)d_in[2];
  const float* w1          = (const float*)d_in[3];
  const float* b1          = (const float*)d_in[4];
  const float* w2          = (const float*)d_in[5];
  const float* b2          = (const float*)d_in[6];
  const float* init_hidden = (const float*)d_in[7];
  float* out = (float*)d_out;

  // largest chunk whose DOUBLE-buffered workspace fits
  int SC = 2048;
  while (SC > 4) {
    size_t need = 2 * ((size_t)SC * 32 * DS2 * 4 + (size_t)SC * 32 * DH * 4)
                + (size_t)B_ * DS * 4;
    if (need <= ws_size) break;
    SC >>= 1;
  }
  float* trans0 = (float*)d_ws;
  float* trans1 = trans0 + (size_t)SC * 32 * DS2;
  float* h1t0   = trans1 + (size_t)SC * 32 * DS2;
  float* h1t1   = h1t0 + (size_t)SC * 32 * DH;
  float* hstate = h1t1 + (size_t)SC * 32 * DH;

  const int M = SC * 32;
  const int nch = S_ / SC;

  // prime: mlp for chunk 0 -> h1t0
  hipLaunchKernelGGL(k_mlp01, dim3(M / 64), dim3(512), 0, stream,
                     actions, w0, b0, w1, b1, h1t0, 0, M);
  // pipelined combined launches
  for (int c = 0; c <= nch; ++c) {
    hipLaunchKernelGGL(k_comb, dim3(256), dim3(512), 0, stream,
                       actions, w0, b0, w1, b1, w2, b2, init_hidden,
                       trans0, trans1, h1t0, h1t1, hstate, out, c, SC, nch);
  }
}